// Round 3
// baseline (553.662 us; speedup 1.0000x reference)
//
#include <hip/hip_runtime.h>

// TemporalAttentionBlock: B=128,S=64,D=1024,H=16,HD=64,FFN=4096
// Pipeline: cvt(x,w*)->bf16 | qkv GEMM | attention | out-proj GEMM | LN1 |
//           FFN1 GEMM (gelu) | FFN2 GEMM | LN2 -> d_out (fp32)
// GEMM: C = A @ W^T + bias, 128x128 tile, 256 thr (2x2 waves of 64x64), BK=32,
// mfma_f32_16x16x32_bf16, global_load_lds width=16 staging.
// R2: LDS double-buffer + source-permuted swizzle (bank-conflict-free: verified
//     SQ_LDS_BANK_CONFLICT 8.4M -> 0).
// R3: XCD-aware block swizzle (1D grid): xcd=blk&7, tm=xcd*8+(j&7), tn=j>>3.
//     Keeps each XCD's 8-panel A-chunk L2-resident across the tn sweep ->
//     beyond-L2 panel traffic 3.07GB -> ~0.75GB (GEMMs were L3-BW-bound).

typedef unsigned short u16;
typedef unsigned int u32;
typedef __attribute__((ext_vector_type(4))) float f32x4;
typedef __attribute__((ext_vector_type(8))) __bf16 bf16x8;

#define DEV static __device__ __forceinline__

DEV u16 f2b(float f) {
  u32 u = __builtin_bit_cast(u32, f);
  u32 r = (u + 0x7FFFu + ((u >> 16) & 1u)) >> 16;
  return (u16)r;
}
DEV float b2f(u16 b) { return __builtin_bit_cast(float, (u32)b << 16); }

DEV void gld16(const u16* g, u16* l) {
  __builtin_amdgcn_global_load_lds(
      (const __attribute__((address_space(1))) u32*)g,
      (__attribute__((address_space(3))) u32*)l, 16, 0, 0);
}

DEV bf16x8 frag8(const u16* p) {
  return __builtin_bit_cast(bf16x8, *(const uint4*)p);
}

// ---------------- fp32 -> bf16 convert (8 elems/thread) ----------------
__global__ __launch_bounds__(256) void cvt_bf16(const float* __restrict__ in,
                                                u16* __restrict__ out, int n8) {
  int i = blockIdx.x * 256 + threadIdx.x;
  if (i >= n8) return;
  const float4* p = (const float4*)in + (size_t)i * 2;
  float4 a = p[0], b = p[1];
  union { u16 s[8]; uint4 u; } o;
  o.s[0] = f2b(a.x); o.s[1] = f2b(a.y); o.s[2] = f2b(a.z); o.s[3] = f2b(a.w);
  o.s[4] = f2b(b.x); o.s[5] = f2b(b.y); o.s[6] = f2b(b.z); o.s[7] = f2b(b.w);
  ((uint4*)out)[i] = o.u;
}

// ---------------- bf16 GEMM: C[M,N] = A[M,K] @ B[N,K]^T + bias ----------------
// ACT: 0 = none, 1 = exact gelu. Output bf16. gm MUST be 64 (M=8192).
// 1D grid of gm*gn blocks; XCD swizzle inside.
template <int ACT>
__global__ __launch_bounds__(256, 2) void gemm_bt(
    const u16* __restrict__ A, const u16* __restrict__ Bm,
    const float* __restrict__ bias, u16* __restrict__ C,
    int N, int K) {
  // XCD swizzle: round-robin dispatch -> blocks with equal (blk&7) share an XCD.
  // Each XCD sweeps its 8 contiguous tm panels (A-chunk, L2-resident) per tn.
  const int blk = blockIdx.x;
  const int xcd = blk & 7;
  const int j = blk >> 3;
  const int tm = xcd * 8 + (j & 7);
  const int tn = j >> 3;

  // [2 bufs][128 rows][4 sub-chunks of 8 elems] ; position = row*4 + swz(sub,row)
  __shared__ __align__(16) u16 As[2][128 * 32];
  __shared__ __align__(16) u16 Bs[2][128 * 32];
  const int tid = threadIdx.x;
  const int lane = tid & 63;
  const int wave = tid >> 6;
  const int wm = wave >> 1, wn = wave & 1;

  f32x4 acc[4][4] = {};

  // staging: LDS position c (0..511) holds data(row=c>>2, sub=((c&3)-(row>>1))&3)
  const int c0 = tid, c1 = tid + 256;
  const int r0 = c0 >> 2, r1 = c1 >> 2;
  const int s0 = ((c0 & 3) - (r0 >> 1)) & 3;
  const int s1 = ((c1 & 3) - (r1 >> 1)) & 3;
  const u16* ga0 = A + (size_t)(tm * 128 + r0) * K + s0 * 8;
  const u16* ga1 = A + (size_t)(tm * 128 + r1) * K + s1 * 8;
  const u16* gb0 = Bm + (size_t)(tn * 128 + r0) * K + s0 * 8;
  const u16* gb1 = Bm + (size_t)(tn * 128 + r1) * K + s1 * 8;
  // wave-uniform LDS bases (HW dest = base + lane*16B)
  const int lo0 = wave * 512;          // elems; chunk-set 0
  const int lo1 = 2048 + wave * 512;   // chunk-set 1

  const int frow = lane & 15;                          // m (or n) in 16-tile
  const int ksw = ((lane >> 4) + (frow >> 1)) & 3;     // swizzled k sub-chunk
  const int aoff = (wm * 64 + frow) * 32 + ksw * 8;
  const int boff = (wn * 64 + frow) * 32 + ksw * 8;

  const int nIter = K >> 5;
  // prologue: stage tile 0 into buf 0
  gld16(ga0, &As[0][lo0]);
  gld16(ga1, &As[0][lo1]);
  gld16(gb0, &Bs[0][lo0]);
  gld16(gb1, &Bs[0][lo1]);
  ga0 += 32; ga1 += 32; gb0 += 32; gb1 += 32;
  __syncthreads();

  for (int kt = 0; kt < nIter; kt++) {
    const int p = kt & 1, q = p ^ 1;
    if (kt + 1 < nIter) {  // prefetch next tile into the other buffer
      gld16(ga0, &As[q][lo0]);
      gld16(ga1, &As[q][lo1]);
      gld16(gb0, &Bs[q][lo0]);
      gld16(gb1, &Bs[q][lo1]);
      ga0 += 32; ga1 += 32; gb0 += 32; gb1 += 32;
    }
    bf16x8 af[4], bq[4];
#pragma unroll
    for (int i = 0; i < 4; i++) af[i] = frag8(&As[p][aoff + i * 512]);
#pragma unroll
    for (int i = 0; i < 4; i++) bq[i] = frag8(&Bs[p][boff + i * 512]);
#pragma unroll
    for (int mt = 0; mt < 4; mt++)
#pragma unroll
      for (int nt = 0; nt < 4; nt++)
        acc[mt][nt] = __builtin_amdgcn_mfma_f32_16x16x32_bf16(
            af[mt], bq[nt], acc[mt][nt], 0, 0, 0);
    __syncthreads();  // reads of buf p done; prefetch into buf q drained
  }

  // C/D layout: col=lane&15, row=(lane>>4)*4+reg
  const int row0 = tm * 128 + wm * 64 + (lane >> 4) * 4;
  const int col0 = tn * 128 + wn * 64 + (lane & 15);
#pragma unroll
  for (int nt = 0; nt < 4; nt++) {
    const int col = col0 + nt * 16;
    const float bv = bias[col];
#pragma unroll
    for (int mt = 0; mt < 4; mt++) {
#pragma unroll
      for (int r = 0; r < 4; r++) {
        const int row = row0 + mt * 16 + r;
        float v = acc[mt][nt][r] + bv;
        if (ACT == 1) v = 0.5f * v * (1.0f + erff(v * 0.70710678118654752f));
        C[(size_t)row * N + col] = f2b(v);
      }
    }
  }
}

// ---------------- attention: one block per (b,h) ----------------
// qkv [8192,3072] bf16; scores fp32 in regs; ctx [8192,1024] bf16
__global__ __launch_bounds__(256) void attn_kernel(
    const u16* __restrict__ qkv, const float* __restrict__ rel,
    u16* __restrict__ ctx) {
  __shared__ float qs[64 * 65];
  __shared__ float ks[64 * 65];
  __shared__ float vs[64 * 65];
  float* ps = qs;  // reuse q's LDS for P after scores (barrier-protected)
  const int tid = threadIdx.x;
  const int bh = blockIdx.x;
  const int b = bh >> 4, h = bh & 15;
  const size_t base = (size_t)b * 64 * 3072 + h * 64;
#pragma unroll
  for (int it = 0; it < 2; it++) {
    int c = tid + it * 256;          // 512 chunks of 8 elems
    int r = c >> 3, cb = (c & 7) * 8;
    const u16* src = &qkv[base + (size_t)r * 3072 + cb];
    uint4 uq = *(const uint4*)(src);
    uint4 uk = *(const uint4*)(src + 1024);
    uint4 uv = *(const uint4*)(src + 2048);
    const u16* q8 = (const u16*)&uq;
    const u16* k8 = (const u16*)&uk;
    const u16* v8 = (const u16*)&uv;
    float* qd = &qs[r * 65 + cb];
    float* kd = &ks[r * 65 + cb];
    float* vd = &vs[r * 65 + cb];
#pragma unroll
    for (int t = 0; t < 8; t++) {
      qd[t] = b2f(q8[t]); kd[t] = b2f(k8[t]); vd[t] = b2f(v8[t]);
    }
  }
  __syncthreads();
  const int i = tid >> 2, jb = (tid & 3) * 16;  // row i, 16 cols per thread
  float s[16];
#pragma unroll
  for (int jj = 0; jj < 16; jj++) s[jj] = 0.f;
  for (int d = 0; d < 64; d++) {
    float qv = qs[i * 65 + d];
#pragma unroll
    for (int jj = 0; jj < 16; jj++) s[jj] += qv * ks[(jb + jj) * 65 + d];
  }
  const float* rb = &rel[((size_t)h * 64 + i) * 64 + jb];
  float mx = -1e30f;
#pragma unroll
  for (int jj = 0; jj < 16; jj++) {
    s[jj] = s[jj] * 0.125f + rb[jj];
    mx = fmaxf(mx, s[jj]);
  }
  mx = fmaxf(mx, __shfl_xor(mx, 1));
  mx = fmaxf(mx, __shfl_xor(mx, 2));
  float sum = 0.f;
#pragma unroll
  for (int jj = 0; jj < 16; jj++) { s[jj] = __expf(s[jj] - mx); sum += s[jj]; }
  sum += __shfl_xor(sum, 1);
  sum += __shfl_xor(sum, 2);
  const float inv = 1.0f / sum;
  __syncthreads();  // all qs reads done before overwriting with P
#pragma unroll
  for (int jj = 0; jj < 16; jj++) ps[i * 65 + jb + jj] = s[jj] * inv;
  __syncthreads();
  float c[16];
#pragma unroll
  for (int t = 0; t < 16; t++) c[t] = 0.f;
  for (int j = 0; j < 64; j++) {
    float pv = ps[i * 65 + j];
#pragma unroll
    for (int t = 0; t < 16; t++) c[t] += pv * vs[j * 65 + jb + t];
  }
  union { u16 s[16]; uint4 u[2]; } o;
#pragma unroll
  for (int t = 0; t < 16; t++) o.s[t] = f2b(c[t]);
  uint4* dst = (uint4*)&ctx[(size_t)(b * 64 + i) * 1024 + h * 64 + jb];
  dst[0] = o.u[0];
  dst[1] = o.u[1];
}

// ---------------- LN1: x1 = LN(x_f32 + attn_bf16) -> bf16 ----------------
__global__ __launch_bounds__(256) void ln1_kernel(
    const float* __restrict__ xres, const u16* __restrict__ add,
    const float* __restrict__ g, const float* __restrict__ be,
    u16* __restrict__ out) {
  const int row = blockIdx.x * 4 + (threadIdx.x >> 6);  // one wave per row
  const int lane = threadIdx.x & 63;
  const float* xr = xres + (size_t)row * 1024;
  const u16* ar = add + (size_t)row * 1024;
  float v[16];
  float sum = 0.f, sq = 0.f;
#pragma unroll
  for (int kk = 0; kk < 2; kk++) {
    const int cb = (lane + 64 * kk) * 8;
    float4 xa = *(const float4*)&xr[cb];
    float4 xb = *(const float4*)&xr[cb + 4];
    uint4 au = *(const uint4*)&ar[cb];
    const u16* a8 = (const u16*)&au;
    float* vv = &v[kk * 8];
    vv[0] = xa.x + b2f(a8[0]); vv[1] = xa.y + b2f(a8[1]);
    vv[2] = xa.z + b2f(a8[2]); vv[3] = xa.w + b2f(a8[3]);
    vv[4] = xb.x + b2f(a8[4]); vv[5] = xb.y + b2f(a8[5]);
    vv[6] = xb.z + b2f(a8[6]); vv[7] = xb.w + b2f(a8[7]);
#pragma unroll
    for (int t = 0; t < 8; t++) { sum += vv[t]; sq += vv[t] * vv[t]; }
  }
#pragma unroll
  for (int o = 1; o < 64; o <<= 1) {
    sum += __shfl_xor(sum, o);
    sq += __shfl_xor(sq, o);
  }
  const float mean = sum * (1.f / 1024.f);
  const float var = sq * (1.f / 1024.f) - mean * mean;
  const float rstd = rsqrtf(var + 1e-5f);
#pragma unroll
  for (int kk = 0; kk < 2; kk++) {
    const int cb = (lane + 64 * kk) * 8;
    float4 ga = *(const float4*)&g[cb];
    float4 gb = *(const float4*)&g[cb + 4];
    float4 ba = *(const float4*)&be[cb];
    float4 bb = *(const float4*)&be[cb + 4];
    const float* vv = &v[kk * 8];
    union { u16 s[8]; uint4 u; } o8;
    o8.s[0] = f2b((vv[0] - mean) * rstd * ga.x + ba.x);
    o8.s[1] = f2b((vv[1] - mean) * rstd * ga.y + ba.y);
    o8.s[2] = f2b((vv[2] - mean) * rstd * ga.z + ba.z);
    o8.s[3] = f2b((vv[3] - mean) * rstd * ga.w + ba.w);
    o8.s[4] = f2b((vv[4] - mean) * rstd * gb.x + bb.x);
    o8.s[5] = f2b((vv[5] - mean) * rstd * gb.y + bb.y);
    o8.s[6] = f2b((vv[6] - mean) * rstd * gb.z + bb.z);
    o8.s[7] = f2b((vv[7] - mean) * rstd * gb.w + bb.w);
    *(uint4*)&out[(size_t)row * 1024 + cb] = o8.u;
  }
}

// ---------------- LN2: out = LN(x1_bf16 + ffn_bf16) -> fp32 (d_out) --------
__global__ __launch_bounds__(256) void ln2_kernel(
    const u16* __restrict__ xres, const u16* __restrict__ add,
    const float* __restrict__ g, const float* __restrict__ be,
    float* __restrict__ out) {
  const int row = blockIdx.x * 4 + (threadIdx.x >> 6);
  const int lane = threadIdx.x & 63;
  const u16* xr = xres + (size_t)row * 1024;
  const u16* ar = add + (size_t)row * 1024;
  float v[16];
  float sum = 0.f, sq = 0.f;
#pragma unroll
  for (int kk = 0; kk < 2; kk++) {
    const int cb = (lane + 64 * kk) * 8;
    uint4 xu = *(const uint4*)&xr[cb];
    uint4 au = *(const uint4*)&ar[cb];
    const u16* x8 = (const u16*)&xu;
    const u16* a8 = (const u16*)&au;
#pragma unroll
    for (int t = 0; t < 8; t++) {
      float f = b2f(x8[t]) + b2f(a8[t]);
      v[kk * 8 + t] = f;
      sum += f;
      sq += f * f;
    }
  }
#pragma unroll
  for (int o = 1; o < 64; o <<= 1) {
    sum += __shfl_xor(sum, o);
    sq += __shfl_xor(sq, o);
  }
  const float mean = sum * (1.f / 1024.f);
  const float var = sq * (1.f / 1024.f) - mean * mean;
  const float rstd = rsqrtf(var + 1e-5f);
#pragma unroll
  for (int kk = 0; kk < 2; kk++) {
    const int cb = (lane + 64 * kk) * 8;
    float4 ga = *(const float4*)&g[cb];
    float4 gb = *(const float4*)&g[cb + 4];
    float4 ba = *(const float4*)&be[cb];
    float4 bb = *(const float4*)&be[cb + 4];
    float4 o0, o1;
    o0.x = (v[kk * 8 + 0] - mean) * rstd * ga.x + ba.x;
    o0.y = (v[kk * 8 + 1] - mean) * rstd * ga.y + ba.y;
    o0.z = (v[kk * 8 + 2] - mean) * rstd * ga.z + ba.z;
    o0.w = (v[kk * 8 + 3] - mean) * rstd * ga.w + ba.w;
    o1.x = (v[kk * 8 + 4] - mean) * rstd * gb.x + bb.x;
    o1.y = (v[kk * 8 + 5] - mean) * rstd * gb.y + bb.y;
    o1.z = (v[kk * 8 + 6] - mean) * rstd * gb.z + bb.z;
    o1.w = (v[kk * 8 + 7] - mean) * rstd * gb.w + bb.w;
    *(float4*)&out[(size_t)row * 1024 + cb] = o0;
    *(float4*)&out[(size_t)row * 1024 + cb + 4] = o1;
  }
}

extern "C" void kernel_launch(void* const* d_in, const int* in_sizes, int n_in,
                              void* d_out, int out_size, void* d_ws,
                              size_t ws_size, hipStream_t stream) {
  const float* x = (const float*)d_in[0];
  const float* w_in = (const float*)d_in[1];
  const float* b_in = (const float*)d_in[2];
  const float* w_out = (const float*)d_in[3];
  const float* b_out = (const float*)d_in[4];
  const float* rel = (const float*)d_in[5];
  const float* g1 = (const float*)d_in[6];
  const float* be1 = (const float*)d_in[7];
  const float* w1 = (const float*)d_in[8];
  const float* b1 = (const float*)d_in[9];
  const float* w2 = (const float*)d_in[10];
  const float* b2 = (const float*)d_in[11];
  const float* g2 = (const float*)d_in[12];
  const float* be2 = (const float*)d_in[13];
  float* out = (float*)d_out;

  u16* ws = (u16*)d_ws;
  // ws layout (u16 units); h aliases qkv+ctx, ffn aliases attn_out
  u16* xb = ws + 0;            // 8,388,608
  u16* winb = ws + 8388608;    // 3,145,728
  u16* woutb = ws + 11534336;  // 1,048,576
  u16* w1b = ws + 12582912;    // 4,194,304
  u16* w2b = ws + 16777216;    // 4,194,304
  u16* qkvb = ws + 20971520;   // 25,165,824  (h: 33,554,432 spans qkv+ctx)
  u16* ctxb = ws + 46137344;   // 8,388,608
  u16* attnb = ws + 54525952;  // 8,388,608   (ffn aliases)
  u16* x1b = ws + 62914560;    // 8,388,608   -> end 71,303,168 u16 = 142.6 MB
  u16* hb = qkvb;
  u16* ffnb = attnb;

  cvt_bf16<<<4096, 256, 0, stream>>>(x, xb, 1048576);
  cvt_bf16<<<1536, 256, 0, stream>>>(w_in, winb, 393216);
  cvt_bf16<<<512, 256, 0, stream>>>(w_out, woutb, 131072);
  cvt_bf16<<<2048, 256, 0, stream>>>(w1, w1b, 524288);
  cvt_bf16<<<2048, 256, 0, stream>>>(w2, w2b, 524288);

  // 1D grids (gm=64 always; gn = N/128)
  gemm_bt<0><<<64 * 24, 256, 0, stream>>>(xb, winb, b_in, qkvb, 3072, 1024);

  attn_kernel<<<2048, 256, 0, stream>>>(qkvb, rel, ctxb);

  gemm_bt<0><<<64 * 8, 256, 0, stream>>>(ctxb, woutb, b_out, attnb, 1024, 1024);

  ln1_kernel<<<2048, 256, 0, stream>>>(x, attnb, g1, be1, x1b);

  gemm_bt<1><<<64 * 32, 256, 0, stream>>>(x1b, w1b, b1, hb, 4096, 1024);

  gemm_bt<0><<<64 * 8, 256, 0, stream>>>(hb, w2b, b2, ffnb, 1024, 4096);

  ln2_kernel<<<2048, 256, 0, stream>>>(x1b, ffnb, g2, be2, out);
}

// Round 4
// 520.611 us; speedup vs baseline: 1.0635x; 1.0635x over previous
//
#include <hip/hip_runtime.h>

// TemporalAttentionBlock: B=128,S=64,D=1024,H=16,HD=64,FFN=4096
// Pipeline: cvt(x,w*)->bf16 | qkv GEMM | attention | out-proj GEMM | LN1 |
//           FFN1 GEMM (gelu) | FFN2 GEMM | LN2 -> d_out (fp32)
// GEMM: C = A @ W^T + bias, 128x128 tile, 256 thr (2x2 waves of 64x64), BK=32,
// mfma_f32_16x16x32_bf16, global_load_lds width=16 staging.
// R2: LDS double-buffer + source-permuted swizzle (SQ_LDS_BANK_CONFLICT 8.4M->0).
// R3: XCD-aware block swizzle (helped big GEMM 137->115us).
// R4: epilogue rework: C-tile through LDS (stride 132, conflict-free) ->
//     full-line uint4 stores (was 2B scatter: 2x HBM write amplification);
//     gelu erff -> tanh-form via __expf (~5x cheaper VALU).

typedef unsigned short u16;
typedef unsigned int u32;
typedef __attribute__((ext_vector_type(4))) float f32x4;
typedef __attribute__((ext_vector_type(8))) __bf16 bf16x8;

#define DEV static __device__ __forceinline__

DEV u16 f2b(float f) {
  u32 u = __builtin_bit_cast(u32, f);
  u32 r = (u + 0x7FFFu + ((u >> 16) & 1u)) >> 16;
  return (u16)r;
}
DEV float b2f(u16 b) { return __builtin_bit_cast(float, (u32)b << 16); }

DEV void gld16(const u16* g, u16* l) {
  __builtin_amdgcn_global_load_lds(
      (const __attribute__((address_space(1))) u32*)g,
      (__attribute__((address_space(3))) u32*)l, 16, 0, 0);
}

DEV bf16x8 frag8(const u16* p) {
  return __builtin_bit_cast(bf16x8, *(const uint4*)p);
}

// ---------------- fp32 -> bf16 convert (8 elems/thread) ----------------
__global__ __launch_bounds__(256) void cvt_bf16(const float* __restrict__ in,
                                                u16* __restrict__ out, int n8) {
  int i = blockIdx.x * 256 + threadIdx.x;
  if (i >= n8) return;
  const float4* p = (const float4*)in + (size_t)i * 2;
  float4 a = p[0], b = p[1];
  union { u16 s[8]; uint4 u; } o;
  o.s[0] = f2b(a.x); o.s[1] = f2b(a.y); o.s[2] = f2b(a.z); o.s[3] = f2b(a.w);
  o.s[4] = f2b(b.x); o.s[5] = f2b(b.y); o.s[6] = f2b(b.z); o.s[7] = f2b(b.w);
  ((uint4*)out)[i] = o.u;
}

// ---------------- bf16 GEMM: C[M,N] = A[M,K] @ B[N,K]^T + bias ----------------
// ACT: 0 = none, 1 = tanh-gelu. Output bf16. gm MUST be 64 (M=8192).
// 1D grid of 64*gn blocks; XCD swizzle inside.
template <int ACT>
__global__ __launch_bounds__(256, 2) void gemm_bt(
    const u16* __restrict__ A, const u16* __restrict__ Bm,
    const float* __restrict__ bias, u16* __restrict__ C,
    int N, int K) {
  // XCD swizzle: round-robin dispatch -> blocks with equal (blk&7) share an XCD.
  const int blk = blockIdx.x;
  const int xcd = blk & 7;
  const int j = blk >> 3;
  const int tm = xcd * 8 + (j & 7);
  const int tn = j >> 3;

  // 33 KB smem: K-loop uses [0,16384) as As/Bs dbuf; epilogue reuses as
  // 128x132 u16 C-tile (pad +4 -> conflict-free rows).
  __shared__ __align__(16) u16 smem[16896];
  u16* As = smem;          // [2][4096]
  u16* Bs = smem + 8192;   // [2][4096]
  u16* Cs = smem;          // [128][132]

  const int tid = threadIdx.x;
  const int lane = tid & 63;
  const int wave = tid >> 6;
  const int wm = wave >> 1, wn = wave & 1;

  f32x4 acc[4][4] = {};

  // staging: LDS position c (0..511) holds data(row=c>>2, sub=((c&3)-(row>>1))&3)
  const int c0 = tid, c1 = tid + 256;
  const int r0 = c0 >> 2, r1 = c1 >> 2;
  const int s0 = ((c0 & 3) - (r0 >> 1)) & 3;
  const int s1 = ((c1 & 3) - (r1 >> 1)) & 3;
  const u16* ga0 = A + (size_t)(tm * 128 + r0) * K + s0 * 8;
  const u16* ga1 = A + (size_t)(tm * 128 + r1) * K + s1 * 8;
  const u16* gb0 = Bm + (size_t)(tn * 128 + r0) * K + s0 * 8;
  const u16* gb1 = Bm + (size_t)(tn * 128 + r1) * K + s1 * 8;
  // wave-uniform LDS bases (HW dest = base + lane*16B)
  const int lo0 = wave * 512;          // elems; chunk-set 0
  const int lo1 = 2048 + wave * 512;   // chunk-set 1

  const int frow = lane & 15;                          // m (or n) in 16-tile
  const int ksw = ((lane >> 4) + (frow >> 1)) & 3;     // swizzled k sub-chunk
  const int aoff = (wm * 64 + frow) * 32 + ksw * 8;
  const int boff = (wn * 64 + frow) * 32 + ksw * 8;

  const int nIter = K >> 5;
  // prologue: stage tile 0 into buf 0
  gld16(ga0, &As[lo0]);
  gld16(ga1, &As[lo1]);
  gld16(gb0, &Bs[lo0]);
  gld16(gb1, &Bs[lo1]);
  ga0 += 32; ga1 += 32; gb0 += 32; gb1 += 32;
  __syncthreads();

  for (int kt = 0; kt < nIter; kt++) {
    const int p = (kt & 1) * 4096, q = p ^ 4096;
    if (kt + 1 < nIter) {  // prefetch next tile into the other buffer
      gld16(ga0, &As[q + lo0]);
      gld16(ga1, &As[q + lo1]);
      gld16(gb0, &Bs[q + lo0]);
      gld16(gb1, &Bs[q + lo1]);
      ga0 += 32; ga1 += 32; gb0 += 32; gb1 += 32;
    }
    bf16x8 af[4], bq[4];
#pragma unroll
    for (int i = 0; i < 4; i++) af[i] = frag8(&As[p + aoff + i * 512]);
#pragma unroll
    for (int i = 0; i < 4; i++) bq[i] = frag8(&Bs[p + boff + i * 512]);
#pragma unroll
    for (int mt = 0; mt < 4; mt++)
#pragma unroll
      for (int nt = 0; nt < 4; nt++)
        acc[mt][nt] = __builtin_amdgcn_mfma_f32_16x16x32_bf16(
            af[mt], bq[nt], acc[mt][nt], 0, 0, 0);
    __syncthreads();  // reads of buf p done; prefetch into buf q drained
  }

  // ---- epilogue: bias+act in regs -> LDS C-tile -> coalesced uint4 stores
  // acc layout: col=lane&15, row=(lane>>4)*4+reg
  const int lr0 = wm * 64 + (lane >> 4) * 4;
  const int lc0 = wn * 64 + (lane & 15);
#pragma unroll
  for (int nt = 0; nt < 4; nt++) {
    const int lc = lc0 + nt * 16;
    const float bv = bias[tn * 128 + lc];
#pragma unroll
    for (int mt = 0; mt < 4; mt++) {
#pragma unroll
      for (int r = 0; r < 4; r++) {
        float v = acc[mt][nt][r] + bv;
        if (ACT == 1) {
          float y = 0.7978845608028654f * (v + 0.044715f * v * v * v);
          float t = 1.f - 2.f / (1.f + __expf(2.f * y));  // tanh(y)
          v = 0.5f * v * (1.f + t);
        }
        Cs[(lr0 + mt * 16 + r) * 132 + lc] = f2b(v);
      }
    }
  }
  __syncthreads();
  // 8 passes, 16 rows/pass; lanes 0-15 cover one row (256 B contiguous)
  const int cr = tid >> 4;
  const int cc = (tid & 15) * 8;
#pragma unroll
  for (int ps = 0; ps < 8; ps++) {
    const int row_l = ps * 16 + cr;
    uint4 val = *(const uint4*)&Cs[row_l * 132 + cc];
    *(uint4*)&C[(size_t)(tm * 128 + row_l) * N + tn * 128 + cc] = val;
  }
}

// ---------------- attention: one block per (b,h) ----------------
// qkv [8192,3072] bf16; scores fp32 in regs; ctx [8192,1024] bf16
__global__ __launch_bounds__(256) void attn_kernel(
    const u16* __restrict__ qkv, const float* __restrict__ rel,
    u16* __restrict__ ctx) {
  __shared__ float qs[64 * 65];
  __shared__ float ks[64 * 65];
  __shared__ float vs[64 * 65];
  float* ps = qs;  // reuse q's LDS for P after scores (barrier-protected)
  const int tid = threadIdx.x;
  const int bh = blockIdx.x;
  const int b = bh >> 4, h = bh & 15;
  const size_t base = (size_t)b * 64 * 3072 + h * 64;
#pragma unroll
  for (int it = 0; it < 2; it++) {
    int c = tid + it * 256;          // 512 chunks of 8 elems
    int r = c >> 3, cb = (c & 7) * 8;
    const u16* src = &qkv[base + (size_t)r * 3072 + cb];
    uint4 uq = *(const uint4*)(src);
    uint4 uk = *(const uint4*)(src + 1024);
    uint4 uv = *(const uint4*)(src + 2048);
    const u16* q8 = (const u16*)&uq;
    const u16* k8 = (const u16*)&uk;
    const u16* v8 = (const u16*)&uv;
    float* qd = &qs[r * 65 + cb];
    float* kd = &ks[r * 65 + cb];
    float* vd = &vs[r * 65 + cb];
#pragma unroll
    for (int t = 0; t < 8; t++) {
      qd[t] = b2f(q8[t]); kd[t] = b2f(k8[t]); vd[t] = b2f(v8[t]);
    }
  }
  __syncthreads();
  const int i = tid >> 2, jb = (tid & 3) * 16;  // row i, 16 cols per thread
  float s[16];
#pragma unroll
  for (int jj = 0; jj < 16; jj++) s[jj] = 0.f;
  for (int d = 0; d < 64; d++) {
    float qv = qs[i * 65 + d];
#pragma unroll
    for (int jj = 0; jj < 16; jj++) s[jj] += qv * ks[(jb + jj) * 65 + d];
  }
  const float* rb = &rel[((size_t)h * 64 + i) * 64 + jb];
  float mx = -1e30f;
#pragma unroll
  for (int jj = 0; jj < 16; jj++) {
    s[jj] = s[jj] * 0.125f + rb[jj];
    mx = fmaxf(mx, s[jj]);
  }
  mx = fmaxf(mx, __shfl_xor(mx, 1));
  mx = fmaxf(mx, __shfl_xor(mx, 2));
  float sum = 0.f;
#pragma unroll
  for (int jj = 0; jj < 16; jj++) { s[jj] = __expf(s[jj] - mx); sum += s[jj]; }
  sum += __shfl_xor(sum, 1);
  sum += __shfl_xor(sum, 2);
  const float inv = 1.0f / sum;
  __syncthreads();  // all qs reads done before overwriting with P
#pragma unroll
  for (int jj = 0; jj < 16; jj++) ps[i * 65 + jb + jj] = s[jj] * inv;
  __syncthreads();
  float c[16];
#pragma unroll
  for (int t = 0; t < 16; t++) c[t] = 0.f;
  for (int j = 0; j < 64; j++) {
    float pv = ps[i * 65 + j];
#pragma unroll
    for (int t = 0; t < 16; t++) c[t] += pv * vs[j * 65 + jb + t];
  }
  union { u16 s[16]; uint4 u[2]; } o;
#pragma unroll
  for (int t = 0; t < 16; t++) o.s[t] = f2b(c[t]);
  uint4* dst = (uint4*)&ctx[(size_t)(b * 64 + i) * 1024 + h * 64 + jb];
  dst[0] = o.u[0];
  dst[1] = o.u[1];
}

// ---------------- LN1: x1 = LN(x_f32 + attn_bf16) -> bf16 ----------------
__global__ __launch_bounds__(256) void ln1_kernel(
    const float* __restrict__ xres, const u16* __restrict__ add,
    const float* __restrict__ g, const float* __restrict__ be,
    u16* __restrict__ out) {
  const int row = blockIdx.x * 4 + (threadIdx.x >> 6);  // one wave per row
  const int lane = threadIdx.x & 63;
  const float* xr = xres + (size_t)row * 1024;
  const u16* ar = add + (size_t)row * 1024;
  float v[16];
  float sum = 0.f, sq = 0.f;
#pragma unroll
  for (int kk = 0; kk < 2; kk++) {
    const int cb = (lane + 64 * kk) * 8;
    float4 xa = *(const float4*)&xr[cb];
    float4 xb = *(const float4*)&xr[cb + 4];
    uint4 au = *(const uint4*)&ar[cb];
    const u16* a8 = (const u16*)&au;
    float* vv = &v[kk * 8];
    vv[0] = xa.x + b2f(a8[0]); vv[1] = xa.y + b2f(a8[1]);
    vv[2] = xa.z + b2f(a8[2]); vv[3] = xa.w + b2f(a8[3]);
    vv[4] = xb.x + b2f(a8[4]); vv[5] = xb.y + b2f(a8[5]);
    vv[6] = xb.z + b2f(a8[6]); vv[7] = xb.w + b2f(a8[7]);
#pragma unroll
    for (int t = 0; t < 8; t++) { sum += vv[t]; sq += vv[t] * vv[t]; }
  }
#pragma unroll
  for (int o = 1; o < 64; o <<= 1) {
    sum += __shfl_xor(sum, o);
    sq += __shfl_xor(sq, o);
  }
  const float mean = sum * (1.f / 1024.f);
  const float var = sq * (1.f / 1024.f) - mean * mean;
  const float rstd = rsqrtf(var + 1e-5f);
#pragma unroll
  for (int kk = 0; kk < 2; kk++) {
    const int cb = (lane + 64 * kk) * 8;
    float4 ga = *(const float4*)&g[cb];
    float4 gb = *(const float4*)&g[cb + 4];
    float4 ba = *(const float4*)&be[cb];
    float4 bb = *(const float4*)&be[cb + 4];
    const float* vv = &v[kk * 8];
    union { u16 s[8]; uint4 u; } o8;
    o8.s[0] = f2b((vv[0] - mean) * rstd * ga.x + ba.x);
    o8.s[1] = f2b((vv[1] - mean) * rstd * ga.y + ba.y);
    o8.s[2] = f2b((vv[2] - mean) * rstd * ga.z + ba.z);
    o8.s[3] = f2b((vv[3] - mean) * rstd * ga.w + ba.w);
    o8.s[4] = f2b((vv[4] - mean) * rstd * gb.x + bb.x);
    o8.s[5] = f2b((vv[5] - mean) * rstd * gb.y + bb.y);
    o8.s[6] = f2b((vv[6] - mean) * rstd * gb.z + bb.z);
    o8.s[7] = f2b((vv[7] - mean) * rstd * gb.w + bb.w);
    *(uint4*)&out[(size_t)row * 1024 + cb] = o8.u;
  }
}

// ---------------- LN2: out = LN(x1_bf16 + ffn_bf16) -> fp32 (d_out) --------
__global__ __launch_bounds__(256) void ln2_kernel(
    const u16* __restrict__ xres, const u16* __restrict__ add,
    const float* __restrict__ g, const float* __restrict__ be,
    float* __restrict__ out) {
  const int row = blockIdx.x * 4 + (threadIdx.x >> 6);
  const int lane = threadIdx.x & 63;
  const u16* xr = xres + (size_t)row * 1024;
  const u16* ar = add + (size_t)row * 1024;
  float v[16];
  float sum = 0.f, sq = 0.f;
#pragma unroll
  for (int kk = 0; kk < 2; kk++) {
    const int cb = (lane + 64 * kk) * 8;
    uint4 xu = *(const uint4*)&xr[cb];
    uint4 au = *(const uint4*)&ar[cb];
    const u16* x8 = (const u16*)&xu;
    const u16* a8 = (const u16*)&au;
#pragma unroll
    for (int t = 0; t < 8; t++) {
      float f = b2f(x8[t]) + b2f(a8[t]);
      v[kk * 8 + t] = f;
      sum += f;
      sq += f * f;
    }
  }
#pragma unroll
  for (int o = 1; o < 64; o <<= 1) {
    sum += __shfl_xor(sum, o);
    sq += __shfl_xor(sq, o);
  }
  const float mean = sum * (1.f / 1024.f);
  const float var = sq * (1.f / 1024.f) - mean * mean;
  const float rstd = rsqrtf(var + 1e-5f);
#pragma unroll
  for (int kk = 0; kk < 2; kk++) {
    const int cb = (lane + 64 * kk) * 8;
    float4 ga = *(const float4*)&g[cb];
    float4 gb = *(const float4*)&g[cb + 4];
    float4 ba = *(const float4*)&be[cb];
    float4 bb = *(const float4*)&be[cb + 4];
    float4 o0, o1;
    o0.x = (v[kk * 8 + 0] - mean) * rstd * ga.x + ba.x;
    o0.y = (v[kk * 8 + 1] - mean) * rstd * ga.y + ba.y;
    o0.z = (v[kk * 8 + 2] - mean) * rstd * ga.z + ba.z;
    o0.w = (v[kk * 8 + 3] - mean) * rstd * ga.w + ba.w;
    o1.x = (v[kk * 8 + 4] - mean) * rstd * gb.x + bb.x;
    o1.y = (v[kk * 8 + 5] - mean) * rstd * gb.y + bb.y;
    o1.z = (v[kk * 8 + 6] - mean) * rstd * gb.z + bb.z;
    o1.w = (v[kk * 8 + 7] - mean) * rstd * gb.w + bb.w;
    *(float4*)&out[(size_t)row * 1024 + cb] = o0;
    *(float4*)&out[(size_t)row * 1024 + cb + 4] = o1;
  }
}

extern "C" void kernel_launch(void* const* d_in, const int* in_sizes, int n_in,
                              void* d_out, int out_size, void* d_ws,
                              size_t ws_size, hipStream_t stream) {
  const float* x = (const float*)d_in[0];
  const float* w_in = (const float*)d_in[1];
  const float* b_in = (const float*)d_in[2];
  const float* w_out = (const float*)d_in[3];
  const float* b_out = (const float*)d_in[4];
  const float* rel = (const float*)d_in[5];
  const float* g1 = (const float*)d_in[6];
  const float* be1 = (const float*)d_in[7];
  const float* w1 = (const float*)d_in[8];
  const float* b1 = (const float*)d_in[9];
  const float* w2 = (const float*)d_in[10];
  const float* b2 = (const float*)d_in[11];
  const float* g2 = (const float*)d_in[12];
  const float* be2 = (const float*)d_in[13];
  float* out = (float*)d_out;

  u16* ws = (u16*)d_ws;
  // ws layout (u16 units); h aliases qkv+ctx, ffn aliases attn_out
  u16* xb = ws + 0;            // 8,388,608
  u16* winb = ws + 8388608;    // 3,145,728
  u16* woutb = ws + 11534336;  // 1,048,576
  u16* w1b = ws + 12582912;    // 4,194,304
  u16* w2b = ws + 16777216;    // 4,194,304
  u16* qkvb = ws + 20971520;   // 25,165,824  (h: 33,554,432 spans qkv+ctx)
  u16* ctxb = ws + 46137344;   // 8,388,608
  u16* attnb = ws + 54525952;  // 8,388,608   (ffn aliases)
  u16* x1b = ws + 62914560;    // 8,388,608   -> end 71,303,168 u16 = 142.6 MB
  u16* hb = qkvb;
  u16* ffnb = attnb;

  cvt_bf16<<<4096, 256, 0, stream>>>(x, xb, 1048576);
  cvt_bf16<<<1536, 256, 0, stream>>>(w_in, winb, 393216);
  cvt_bf16<<<512, 256, 0, stream>>>(w_out, woutb, 131072);
  cvt_bf16<<<2048, 256, 0, stream>>>(w1, w1b, 524288);
  cvt_bf16<<<2048, 256, 0, stream>>>(w2, w2b, 524288);

  // 1D grids (gm=64 always; gn = N/128)
  gemm_bt<0><<<64 * 24, 256, 0, stream>>>(xb, winb, b_in, qkvb, 3072, 1024);

  attn_kernel<<<2048, 256, 0, stream>>>(qkvb, rel, ctxb);

  gemm_bt<0><<<64 * 8, 256, 0, stream>>>(ctxb, woutb, b_out, attnb, 1024, 1024);

  ln1_kernel<<<2048, 256, 0, stream>>>(x, attnb, g1, be1, x1b);

  gemm_bt<1><<<64 * 32, 256, 0, stream>>>(x1b, w1b, b1, hb, 4096, 1024);

  gemm_bt<0><<<64 * 8, 256, 0, stream>>>(hb, w2b, b2, ffnb, 1024, 4096);

  ln2_kernel<<<2048, 256, 0, stream>>>(x1b, ffnb, g2, be2, out);
}

// Round 5
// 446.959 us; speedup vs baseline: 1.2387x; 1.1648x over previous
//
#include <hip/hip_runtime.h>

// TemporalAttentionBlock: B=128,S=64,D=1024,H=16,HD=64,FFN=4096
// Pipeline: cvt(x,w*)->bf16 | qkv GEMM | attention | out-proj GEMM | LN1 |
//           FFN1 GEMM (gelu) | FFN2 GEMM | LN2 -> d_out (fp32)
// GEMM: C = A @ W^T + bias, 128x128 tile, 256 thr (2x2 waves of 64x64), BK=32,
// mfma_f32_16x16x32_bf16, global_load_lds width=16 staging.
// R2: LDS double-buffer + source-permuted swizzle (SQ_LDS_BANK_CONFLICT 8.4M->0).
// R3: XCD-aware block swizzle (big GEMM 137->115us).
// R4: GEMM epilogue via LDS -> full-line uint4 stores; tanh-gelu.
// R5: MFMA attention (was pure-VALU, 111us, MfmaUtil=0): S=Q@K^T and P@V on
//     matrix cores; V^T staged via coalesced global column loads; P through
//     LDS (pad 72); swizzled staging for conflict-free ds_read_b128.

typedef unsigned short u16;
typedef unsigned int u32;
typedef __attribute__((ext_vector_type(4))) float f32x4;
typedef __attribute__((ext_vector_type(8))) __bf16 bf16x8;

#define DEV static __device__ __forceinline__

DEV u16 f2b(float f) {
  u32 u = __builtin_bit_cast(u32, f);
  u32 r = (u + 0x7FFFu + ((u >> 16) & 1u)) >> 16;
  return (u16)r;
}
DEV float b2f(u16 b) { return __builtin_bit_cast(float, (u32)b << 16); }

DEV void gld16(const u16* g, u16* l) {
  __builtin_amdgcn_global_load_lds(
      (const __attribute__((address_space(1))) u32*)g,
      (__attribute__((address_space(3))) u32*)l, 16, 0, 0);
}

DEV bf16x8 frag8(const u16* p) {
  return __builtin_bit_cast(bf16x8, *(const uint4*)p);
}

// ---------------- fp32 -> bf16 convert (8 elems/thread) ----------------
__global__ __launch_bounds__(256) void cvt_bf16(const float* __restrict__ in,
                                                u16* __restrict__ out, int n8) {
  int i = blockIdx.x * 256 + threadIdx.x;
  if (i >= n8) return;
  const float4* p = (const float4*)in + (size_t)i * 2;
  float4 a = p[0], b = p[1];
  union { u16 s[8]; uint4 u; } o;
  o.s[0] = f2b(a.x); o.s[1] = f2b(a.y); o.s[2] = f2b(a.z); o.s[3] = f2b(a.w);
  o.s[4] = f2b(b.x); o.s[5] = f2b(b.y); o.s[6] = f2b(b.z); o.s[7] = f2b(b.w);
  ((uint4*)out)[i] = o.u;
}

// ---------------- bf16 GEMM: C[M,N] = A[M,K] @ B[N,K]^T + bias ----------------
// ACT: 0 = none, 1 = tanh-gelu. Output bf16. gm MUST be 64 (M=8192).
template <int ACT>
__global__ __launch_bounds__(256, 2) void gemm_bt(
    const u16* __restrict__ A, const u16* __restrict__ Bm,
    const float* __restrict__ bias, u16* __restrict__ C,
    int N, int K) {
  const int blk = blockIdx.x;
  const int xcd = blk & 7;
  const int j = blk >> 3;
  const int tm = xcd * 8 + (j & 7);
  const int tn = j >> 3;

  __shared__ __align__(16) u16 smem[16896];
  u16* As = smem;          // [2][4096]
  u16* Bs = smem + 8192;   // [2][4096]
  u16* Cs = smem;          // epilogue: [128][132]

  const int tid = threadIdx.x;
  const int lane = tid & 63;
  const int wave = tid >> 6;
  const int wm = wave >> 1, wn = wave & 1;

  f32x4 acc[4][4] = {};

  const int c0 = tid, c1 = tid + 256;
  const int r0 = c0 >> 2, r1 = c1 >> 2;
  const int s0 = ((c0 & 3) - (r0 >> 1)) & 3;
  const int s1 = ((c1 & 3) - (r1 >> 1)) & 3;
  const u16* ga0 = A + (size_t)(tm * 128 + r0) * K + s0 * 8;
  const u16* ga1 = A + (size_t)(tm * 128 + r1) * K + s1 * 8;
  const u16* gb0 = Bm + (size_t)(tn * 128 + r0) * K + s0 * 8;
  const u16* gb1 = Bm + (size_t)(tn * 128 + r1) * K + s1 * 8;
  const int lo0 = wave * 512;
  const int lo1 = 2048 + wave * 512;

  const int frow = lane & 15;
  const int ksw = ((lane >> 4) + (frow >> 1)) & 3;
  const int aoff = (wm * 64 + frow) * 32 + ksw * 8;
  const int boff = (wn * 64 + frow) * 32 + ksw * 8;

  const int nIter = K >> 5;
  gld16(ga0, &As[lo0]);
  gld16(ga1, &As[lo1]);
  gld16(gb0, &Bs[lo0]);
  gld16(gb1, &Bs[lo1]);
  ga0 += 32; ga1 += 32; gb0 += 32; gb1 += 32;
  __syncthreads();

  for (int kt = 0; kt < nIter; kt++) {
    const int p = (kt & 1) * 4096, q = p ^ 4096;
    if (kt + 1 < nIter) {
      gld16(ga0, &As[q + lo0]);
      gld16(ga1, &As[q + lo1]);
      gld16(gb0, &Bs[q + lo0]);
      gld16(gb1, &Bs[q + lo1]);
      ga0 += 32; ga1 += 32; gb0 += 32; gb1 += 32;
    }
    bf16x8 af[4], bq[4];
#pragma unroll
    for (int i = 0; i < 4; i++) af[i] = frag8(&As[p + aoff + i * 512]);
#pragma unroll
    for (int i = 0; i < 4; i++) bq[i] = frag8(&Bs[p + boff + i * 512]);
#pragma unroll
    for (int mt = 0; mt < 4; mt++)
#pragma unroll
      for (int nt = 0; nt < 4; nt++)
        acc[mt][nt] = __builtin_amdgcn_mfma_f32_16x16x32_bf16(
            af[mt], bq[nt], acc[mt][nt], 0, 0, 0);
    __syncthreads();
  }

  const int lr0 = wm * 64 + (lane >> 4) * 4;
  const int lc0 = wn * 64 + (lane & 15);
#pragma unroll
  for (int nt = 0; nt < 4; nt++) {
    const int lc = lc0 + nt * 16;
    const float bv = bias[tn * 128 + lc];
#pragma unroll
    for (int mt = 0; mt < 4; mt++) {
#pragma unroll
      for (int r = 0; r < 4; r++) {
        float v = acc[mt][nt][r] + bv;
        if (ACT == 1) {
          float y = 0.7978845608028654f * (v + 0.044715f * v * v * v);
          float t = 1.f - 2.f / (1.f + __expf(2.f * y));  // tanh(y)
          v = 0.5f * v * (1.f + t);
        }
        Cs[(lr0 + mt * 16 + r) * 132 + lc] = f2b(v);
      }
    }
  }
  __syncthreads();
  const int cr = tid >> 4;
  const int cc = (tid & 15) * 8;
#pragma unroll
  for (int ps = 0; ps < 8; ps++) {
    const int row_l = ps * 16 + cr;
    uint4 val = *(const uint4*)&Cs[row_l * 132 + cc];
    *(uint4*)&C[(size_t)(tm * 128 + row_l) * N + tn * 128 + cc] = val;
  }
}

// ---------------- MFMA attention: one block per (b,h) ----------------
// qkv [8192,3072] bf16 -> ctx [8192,1024] bf16. 4 waves; wave w owns q rows
// [w*16,w*16+16). S=Q@K^T (mfma), softmax in C-layout, P->LDS bf16, P@V (mfma)
// with V^T staged from global via coalesced 128B column-segment loads.
__global__ __launch_bounds__(256) void attn_kernel(
    const u16* __restrict__ qkv, const float* __restrict__ rel,
    u16* __restrict__ ctx) {
  // qs/ks: [64 rows][8 slots of 8 elems], slot=(sub+row)&7 swizzle
  __shared__ __align__(16) u16 qs[4096];
  __shared__ __align__(16) u16 ks[4096];
  __shared__ __align__(16) u16 vt[64 * 72];   // V^T [hd][key], pad 72
  __shared__ __align__(16) u16 ps[4 * 16 * 72];  // per-wave P [q][key], pad 72
  const int tid = threadIdx.x;
  const int lane = tid & 63;
  const int wave = tid >> 6;
  const int quad = lane >> 4;
  const int l15 = lane & 15;
  const int bh = blockIdx.x;
  const int b = bh >> 4, h = bh & 15;
  const size_t base = (size_t)b * 64 * 3072 + h * 64;

  // ---- stage Q,K via gld16 (swizzled source), V^T via coalesced u16 loads
  {
    const int cA = tid, cB = tid + 256;
    const int rA = cA >> 3, sA = ((cA & 7) - rA) & 7;
    const int rB = cB >> 3, sB = ((cB & 7) - rB) & 7;
    const u16* gA = qkv + base + (size_t)rA * 3072 + sA * 8;
    const u16* gB = qkv + base + (size_t)rB * 3072 + sB * 8;
    gld16(gA, &qs[wave * 512]);
    gld16(gB, &qs[2048 + wave * 512]);
    gld16(gA + 1024, &ks[wave * 512]);
    gld16(gB + 1024, &ks[2048 + wave * 512]);
  }
  {
    const int hd = tid & 63;
    const int kg0 = tid >> 6;  // 0..3
#pragma unroll
    for (int half = 0; half < 2; half++) {
      const int kg = kg0 + half * 4;
      union { u16 s[8]; uint4 u; } o;
#pragma unroll
      for (int t = 0; t < 8; t++)
        o.s[t] = qkv[base + (size_t)(kg * 8 + t) * 3072 + 2048 + hd];
      *(uint4*)&vt[hd * 72 + kg * 8] = o.u;
    }
  }
  __syncthreads();

  // ---- scores S[16q x 64k] = Q @ K^T (per wave)
  const int qrow = wave * 16 + l15;
  bf16x8 aq[2];
#pragma unroll
  for (int kc = 0; kc < 2; kc++)
    aq[kc] = frag8(&qs[qrow * 64 + (((kc * 4 + quad) + qrow) & 7) * 8]);
  f32x4 accs[4] = {};
#pragma unroll
  for (int nt = 0; nt < 4; nt++) {
    const int krow = nt * 16 + l15;
#pragma unroll
    for (int kc = 0; kc < 2; kc++) {
      bf16x8 bk = frag8(&ks[krow * 64 + (((kc * 4 + quad) + krow) & 7) * 8]);
      accs[nt] =
          __builtin_amdgcn_mfma_f32_16x16x32_bf16(aq[kc], bk, accs[nt], 0, 0, 0);
    }
  }

  // ---- softmax over keys (C-layout: row=quad*4+r, col=nt*16+l15)
  const int qg = wave * 16 + quad * 4;  // + r
  float pm[4][4], mx[4], sm[4];
#pragma unroll
  for (int r = 0; r < 4; r++) mx[r] = -1e30f;
#pragma unroll
  for (int nt = 0; nt < 4; nt++) {
    const float* rb = &rel[((size_t)h * 64 + qg) * 64 + nt * 16 + l15];
#pragma unroll
    for (int r = 0; r < 4; r++) {
      float v = accs[nt][r] * 0.125f + rb[r * 64];
      pm[nt][r] = v;
      mx[r] = fmaxf(mx[r], v);
    }
  }
#pragma unroll
  for (int r = 0; r < 4; r++) {
    mx[r] = fmaxf(mx[r], __shfl_xor(mx[r], 1));
    mx[r] = fmaxf(mx[r], __shfl_xor(mx[r], 2));
    mx[r] = fmaxf(mx[r], __shfl_xor(mx[r], 4));
    mx[r] = fmaxf(mx[r], __shfl_xor(mx[r], 8));
    sm[r] = 0.f;
  }
#pragma unroll
  for (int nt = 0; nt < 4; nt++)
#pragma unroll
    for (int r = 0; r < 4; r++) {
      float e = __expf(pm[nt][r] - mx[r]);
      pm[nt][r] = e;
      sm[r] += e;
    }
#pragma unroll
  for (int r = 0; r < 4; r++) {
    sm[r] += __shfl_xor(sm[r], 1);
    sm[r] += __shfl_xor(sm[r], 2);
    sm[r] += __shfl_xor(sm[r], 4);
    sm[r] += __shfl_xor(sm[r], 8);
    sm[r] = 1.f / sm[r];
  }
  u16* psw = &ps[wave * 1152];
#pragma unroll
  for (int nt = 0; nt < 4; nt++)
#pragma unroll
    for (int r = 0; r < 4; r++)
      psw[(quad * 4 + r) * 72 + nt * 16 + l15] = f2b(pm[nt][r] * sm[r]);
  __syncthreads();

  // ---- ctx[16q x 64hd] = P @ V  (B-frag from vt rows = V^T rows)
  bf16x8 ap[2];
#pragma unroll
  for (int kc = 0; kc < 2; kc++)
    ap[kc] = frag8(&psw[l15 * 72 + kc * 32 + quad * 8]);
  f32x4 accc[4] = {};
#pragma unroll
  for (int nt = 0; nt < 4; nt++) {
    const int hdr = nt * 16 + l15;
#pragma unroll
    for (int kc = 0; kc < 2; kc++) {
      bf16x8 bv = frag8(&vt[hdr * 72 + kc * 32 + quad * 8]);
      accc[nt] =
          __builtin_amdgcn_mfma_f32_16x16x32_bf16(ap[kc], bv, accc[nt], 0, 0, 0);
    }
  }
  // ctx -> qs overlay (swizzled), then coalesced uint4 stores
#pragma unroll
  for (int nt = 0; nt < 4; nt++)
#pragma unroll
    for (int r = 0; r < 4; r++) {
      const int rowq = wave * 16 + quad * 4 + r;
      const int hd = nt * 16 + l15;
      qs[rowq * 64 + (((hd >> 3) + rowq) & 7) * 8 + (hd & 7)] = f2b(accc[nt][r]);
    }
  __syncthreads();
#pragma unroll
  for (int half = 0; half < 2; half++) {
    const int c = tid + half * 256;
    const int row = c >> 3, sub = c & 7;
    uint4 val = *(const uint4*)&qs[row * 64 + ((sub + row) & 7) * 8];
    *(uint4*)&ctx[(size_t)(b * 64 + row) * 1024 + h * 64 + sub * 8] = val;
  }
}

// ---------------- LN1: x1 = LN(x_f32 + attn_bf16) -> bf16 ----------------
__global__ __launch_bounds__(256) void ln1_kernel(
    const float* __restrict__ xres, const u16* __restrict__ add,
    const float* __restrict__ g, const float* __restrict__ be,
    u16* __restrict__ out) {
  const int row = blockIdx.x * 4 + (threadIdx.x >> 6);
  const int lane = threadIdx.x & 63;
  const float* xr = xres + (size_t)row * 1024;
  const u16* ar = add + (size_t)row * 1024;
  float v[16];
  float sum = 0.f, sq = 0.f;
#pragma unroll
  for (int kk = 0; kk < 2; kk++) {
    const int cb = (lane + 64 * kk) * 8;
    float4 xa = *(const float4*)&xr[cb];
    float4 xb = *(const float4*)&xr[cb + 4];
    uint4 au = *(const uint4*)&ar[cb];
    const u16* a8 = (const u16*)&au;
    float* vv = &v[kk * 8];
    vv[0] = xa.x + b2f(a8[0]); vv[1] = xa.y + b2f(a8[1]);
    vv[2] = xa.z + b2f(a8[2]); vv[3] = xa.w + b2f(a8[3]);
    vv[4] = xb.x + b2f(a8[4]); vv[5] = xb.y + b2f(a8[5]);
    vv[6] = xb.z + b2f(a8[6]); vv[7] = xb.w + b2f(a8[7]);
#pragma unroll
    for (int t = 0; t < 8; t++) { sum += vv[t]; sq += vv[t] * vv[t]; }
  }
#pragma unroll
  for (int o = 1; o < 64; o <<= 1) {
    sum += __shfl_xor(sum, o);
    sq += __shfl_xor(sq, o);
  }
  const float mean = sum * (1.f / 1024.f);
  const float var = sq * (1.f / 1024.f) - mean * mean;
  const float rstd = rsqrtf(var + 1e-5f);
#pragma unroll
  for (int kk = 0; kk < 2; kk++) {
    const int cb = (lane + 64 * kk) * 8;
    float4 ga = *(const float4*)&g[cb];
    float4 gb = *(const float4*)&g[cb + 4];
    float4 ba = *(const float4*)&be[cb];
    float4 bb = *(const float4*)&be[cb + 4];
    const float* vv = &v[kk * 8];
    union { u16 s[8]; uint4 u; } o8;
    o8.s[0] = f2b((vv[0] - mean) * rstd * ga.x + ba.x);
    o8.s[1] = f2b((vv[1] - mean) * rstd * ga.y + ba.y);
    o8.s[2] = f2b((vv[2] - mean) * rstd * ga.z + ba.z);
    o8.s[3] = f2b((vv[3] - mean) * rstd * ga.w + ba.w);
    o8.s[4] = f2b((vv[4] - mean) * rstd * gb.x + bb.x);
    o8.s[5] = f2b((vv[5] - mean) * rstd * gb.y + bb.y);
    o8.s[6] = f2b((vv[6] - mean) * rstd * gb.z + bb.z);
    o8.s[7] = f2b((vv[7] - mean) * rstd * gb.w + bb.w);
    *(uint4*)&out[(size_t)row * 1024 + cb] = o8.u;
  }
}

// ---------------- LN2: out = LN(x1_bf16 + ffn_bf16) -> fp32 (d_out) --------
__global__ __launch_bounds__(256) void ln2_kernel(
    const u16* __restrict__ xres, const u16* __restrict__ add,
    const float* __restrict__ g, const float* __restrict__ be,
    float* __restrict__ out) {
  const int row = blockIdx.x * 4 + (threadIdx.x >> 6);
  const int lane = threadIdx.x & 63;
  const u16* xr = xres + (size_t)row * 1024;
  const u16* ar = add + (size_t)row * 1024;
  float v[16];
  float sum = 0.f, sq = 0.f;
#pragma unroll
  for (int kk = 0; kk < 2; kk++) {
    const int cb = (lane + 64 * kk) * 8;
    uint4 xu = *(const uint4*)&xr[cb];
    uint4 au = *(const uint4*)&ar[cb];
    const u16* x8 = (const u16*)&xu;
    const u16* a8 = (const u16*)&au;
#pragma unroll
    for (int t = 0; t < 8; t++) {
      float f = b2f(x8[t]) + b2f(a8[t]);
      v[kk * 8 + t] = f;
      sum += f;
      sq += f * f;
    }
  }
#pragma unroll
  for (int o = 1; o < 64; o <<= 1) {
    sum += __shfl_xor(sum, o);
    sq += __shfl_xor(sq, o);
  }
  const float mean = sum * (1.f / 1024.f);
  const float var = sq * (1.f / 1024.f) - mean * mean;
  const float rstd = rsqrtf(var + 1e-5f);
#pragma unroll
  for (int kk = 0; kk < 2; kk++) {
    const int cb = (lane + 64 * kk) * 8;
    float4 ga = *(const float4*)&g[cb];
    float4 gb = *(const float4*)&g[cb + 4];
    float4 ba = *(const float4*)&be[cb];
    float4 bb = *(const float4*)&be[cb + 4];
    float4 o0, o1;
    o0.x = (v[kk * 8 + 0] - mean) * rstd * ga.x + ba.x;
    o0.y = (v[kk * 8 + 1] - mean) * rstd * ga.y + ba.y;
    o0.z = (v[kk * 8 + 2] - mean) * rstd * ga.z + ba.z;
    o0.w = (v[kk * 8 + 3] - mean) * rstd * ga.w + ba.w;
    o1.x = (v[kk * 8 + 4] - mean) * rstd * gb.x + bb.x;
    o1.y = (v[kk * 8 + 5] - mean) * rstd * gb.y + bb.y;
    o1.z = (v[kk * 8 + 6] - mean) * rstd * gb.z + bb.z;
    o1.w = (v[kk * 8 + 7] - mean) * rstd * gb.w + bb.w;
    *(float4*)&out[(size_t)row * 1024 + cb] = o0;
    *(float4*)&out[(size_t)row * 1024 + cb + 4] = o1;
  }
}

extern "C" void kernel_launch(void* const* d_in, const int* in_sizes, int n_in,
                              void* d_out, int out_size, void* d_ws,
                              size_t ws_size, hipStream_t stream) {
  const float* x = (const float*)d_in[0];
  const float* w_in = (const float*)d_in[1];
  const float* b_in = (const float*)d_in[2];
  const float* w_out = (const float*)d_in[3];
  const float* b_out = (const float*)d_in[4];
  const float* rel = (const float*)d_in[5];
  const float* g1 = (const float*)d_in[6];
  const float* be1 = (const float*)d_in[7];
  const float* w1 = (const float*)d_in[8];
  const float* b1 = (const float*)d_in[9];
  const float* w2 = (const float*)d_in[10];
  const float* b2 = (const float*)d_in[11];
  const float* g2 = (const float*)d_in[12];
  const float* be2 = (const float*)d_in[13];
  float* out = (float*)d_out;

  u16* ws = (u16*)d_ws;
  u16* xb = ws + 0;            // 8,388,608
  u16* winb = ws + 8388608;    // 3,145,728
  u16* woutb = ws + 11534336;  // 1,048,576
  u16* w1b = ws + 12582912;    // 4,194,304
  u16* w2b = ws + 16777216;    // 4,194,304
  u16* qkvb = ws + 20971520;   // 25,165,824  (h aliases qkv+ctx)
  u16* ctxb = ws + 46137344;   // 8,388,608
  u16* attnb = ws + 54525952;  // 8,388,608   (ffn aliases)
  u16* x1b = ws + 62914560;    // 8,388,608
  u16* hb = qkvb;
  u16* ffnb = attnb;

  cvt_bf16<<<4096, 256, 0, stream>>>(x, xb, 1048576);
  cvt_bf16<<<1536, 256, 0, stream>>>(w_in, winb, 393216);
  cvt_bf16<<<512, 256, 0, stream>>>(w_out, woutb, 131072);
  cvt_bf16<<<2048, 256, 0, stream>>>(w1, w1b, 524288);
  cvt_bf16<<<2048, 256, 0, stream>>>(w2, w2b, 524288);

  gemm_bt<0><<<64 * 24, 256, 0, stream>>>(xb, winb, b_in, qkvb, 3072, 1024);

  attn_kernel<<<2048, 256, 0, stream>>>(qkvb, rel, ctxb);

  gemm_bt<0><<<64 * 8, 256, 0, stream>>>(ctxb, woutb, b_out, attnb, 1024, 1024);

  ln1_kernel<<<2048, 256, 0, stream>>>(x, attnb, g1, be1, x1b);

  gemm_bt<1><<<64 * 32, 256, 0, stream>>>(x1b, w1b, b1, hb, 4096, 1024);

  gemm_bt<0><<<64 * 8, 256, 0, stream>>>(hb, w2b, b2, ffnb, 1024, 4096);

  ln2_kernel<<<2048, 256, 0, stream>>>(x1b, ffnb, g2, be2, out);
}

// Round 6
// 420.293 us; speedup vs baseline: 1.3173x; 1.0634x over previous
//
#include <hip/hip_runtime.h>

// TemporalAttentionBlock: B=128,S=64,D=1024,H=16,HD=64,FFN=4096
// Pipeline: cvt5(x,w*)->bf16 | qkv GEMM | attention(MFMA) | out-proj GEMM |
//           LN1 | FFN1 GEMM (gelu) | FFN2 GEMM | LN2 -> d_out (fp32)
// GEMM: C = A @ W^T + bias, 128x128 tile, 256 thr (2x2 waves of 64x64), BK=32,
// mfma_f32_16x16x32_bf16, global_load_lds width=16 staging.
// R2: LDS double-buffer + source-permuted swizzle (SQ_LDS_BANK_CONFLICT 8.4M->0).
// R3: XCD-aware block swizzle (big GEMM 137->115us).
// R4: GEMM epilogue via LDS -> full-line uint4 stores; tanh-gelu.
// R5: MFMA attention (111us -> off the profile).
// R6: LDS trimmed to exactly 32KB (XOR-swizzled epilogue overlay, no pad) +
//     launch_bounds(256,4) -> target 4 blocks/CU (was 35% occ, latency-bound);
//     fused cvt (1 launch); LN1 reads bf16 x.

typedef unsigned short u16;
typedef unsigned int u32;
typedef __attribute__((ext_vector_type(4))) float f32x4;
typedef __attribute__((ext_vector_type(8))) __bf16 bf16x8;

#define DEV static __device__ __forceinline__

DEV u16 f2b(float f) {
  u32 u = __builtin_bit_cast(u32, f);
  u32 r = (u + 0x7FFFu + ((u >> 16) & 1u)) >> 16;
  return (u16)r;
}
DEV float b2f(u16 b) { return __builtin_bit_cast(float, (u32)b << 16); }

DEV void gld16(const u16* g, u16* l) {
  __builtin_amdgcn_global_load_lds(
      (const __attribute__((address_space(1))) u32*)g,
      (__attribute__((address_space(3))) u32*)l, 16, 0, 0);
}

DEV bf16x8 frag8(const u16* p) {
  return __builtin_bit_cast(bf16x8, *(const uint4*)p);
}

// ---------------- fused fp32 -> bf16 convert (5 regions, 8 elems/thread) ----
struct Cvt5 {
  const float *s0, *s1, *s2, *s3, *s4;
  u16 *d0, *d1, *d2, *d3, *d4;
};
// region ends (n8 units): x 1048576 | w_in 393216 | w_out 131072 | w1 524288 |
// w2 524288 ; cumulative: 1048576,1441792,1572864,2097152,2621440
__global__ __launch_bounds__(256) void cvt5_kernel(Cvt5 a) {
  int i = blockIdx.x * 256 + threadIdx.x;
  const float* s;
  u16* d;
  int j = i;
  if (i < 1048576) { s = a.s0; d = a.d0; }
  else if (i < 1441792) { s = a.s1; d = a.d1; j = i - 1048576; }
  else if (i < 1572864) { s = a.s2; d = a.d2; j = i - 1441792; }
  else if (i < 2097152) { s = a.s3; d = a.d3; j = i - 1572864; }
  else { s = a.s4; d = a.d4; j = i - 2097152; }
  const float4* p = (const float4*)s + (size_t)j * 2;
  float4 va = p[0], vb = p[1];
  union { u16 s[8]; uint4 u; } o;
  o.s[0] = f2b(va.x); o.s[1] = f2b(va.y); o.s[2] = f2b(va.z); o.s[3] = f2b(va.w);
  o.s[4] = f2b(vb.x); o.s[5] = f2b(vb.y); o.s[6] = f2b(vb.z); o.s[7] = f2b(vb.w);
  ((uint4*)d)[j] = o.u;
}

// ---------------- bf16 GEMM: C[M,N] = A[M,K] @ B[N,K]^T + bias ----------------
// ACT: 0 = none, 1 = tanh-gelu. Output bf16. gm MUST be 64 (M=8192).
template <int ACT>
__global__ __launch_bounds__(256, 4) void gemm_bt(
    const u16* __restrict__ A, const u16* __restrict__ Bm,
    const float* __restrict__ bias, u16* __restrict__ C,
    int N, int K) {
  const int blk = blockIdx.x;
  const int xcd = blk & 7;
  const int j = blk >> 3;
  const int tm = xcd * 8 + (j & 7);
  const int tn = j >> 3;

  // exactly 32 KB: K-loop As/Bs dbuf; epilogue overlays as 128x128 u16 C-tile
  // with XOR block swizzle (16B block b of row r at ((b + ((r&15)>>2)*2)&15)).
  __shared__ __align__(16) u16 smem[16384];
  u16* As = smem;          // [2][4096]
  u16* Bs = smem + 8192;   // [2][4096]
  u16* Cs = smem;          // epilogue overlay

  const int tid = threadIdx.x;
  const int lane = tid & 63;
  const int wave = tid >> 6;
  const int wm = wave >> 1, wn = wave & 1;

  f32x4 acc[4][4] = {};

  const int c0 = tid, c1 = tid + 256;
  const int r0 = c0 >> 2, r1 = c1 >> 2;
  const int s0 = ((c0 & 3) - (r0 >> 1)) & 3;
  const int s1 = ((c1 & 3) - (r1 >> 1)) & 3;
  const u16* ga0 = A + (size_t)(tm * 128 + r0) * K + s0 * 8;
  const u16* ga1 = A + (size_t)(tm * 128 + r1) * K + s1 * 8;
  const u16* gb0 = Bm + (size_t)(tn * 128 + r0) * K + s0 * 8;
  const u16* gb1 = Bm + (size_t)(tn * 128 + r1) * K + s1 * 8;
  const int lo0 = wave * 512;
  const int lo1 = 2048 + wave * 512;

  const int frow = lane & 15;
  const int ksw = ((lane >> 4) + (frow >> 1)) & 3;
  const int aoff = (wm * 64 + frow) * 32 + ksw * 8;
  const int boff = (wn * 64 + frow) * 32 + ksw * 8;

  const int nIter = K >> 5;
  gld16(ga0, &As[lo0]);
  gld16(ga1, &As[lo1]);
  gld16(gb0, &Bs[lo0]);
  gld16(gb1, &Bs[lo1]);
  ga0 += 32; ga1 += 32; gb0 += 32; gb1 += 32;
  __syncthreads();

  for (int kt = 0; kt < nIter; kt++) {
    const int p = (kt & 1) * 4096, q = p ^ 4096;
    if (kt + 1 < nIter) {
      gld16(ga0, &As[q + lo0]);
      gld16(ga1, &As[q + lo1]);
      gld16(gb0, &Bs[q + lo0]);
      gld16(gb1, &Bs[q + lo1]);
      ga0 += 32; ga1 += 32; gb0 += 32; gb1 += 32;
    }
    bf16x8 af[4], bq[4];
#pragma unroll
    for (int i = 0; i < 4; i++) af[i] = frag8(&As[p + aoff + i * 512]);
#pragma unroll
    for (int i = 0; i < 4; i++) bq[i] = frag8(&Bs[p + boff + i * 512]);
#pragma unroll
    for (int mt = 0; mt < 4; mt++)
#pragma unroll
      for (int nt = 0; nt < 4; nt++)
        acc[mt][nt] = __builtin_amdgcn_mfma_f32_16x16x32_bf16(
            af[mt], bq[nt], acc[mt][nt], 0, 0, 0);
    __syncthreads();
  }

  // ---- epilogue: bias+act in regs -> swizzled LDS C-tile -> uint4 stores
  // acc layout: col=lane&15, row=(lane>>4)*4+reg
  const int quad = lane >> 4;
  const int lr0 = wm * 64 + quad * 4;
  const int lc0 = wn * 64 + (lane & 15);
#pragma unroll
  for (int nt = 0; nt < 4; nt++) {
    const int lc = lc0 + nt * 16;
    const float bv = bias[tn * 128 + lc];
    const int pb = ((lc >> 3) + quad * 2) & 15;  // swizzled 16B block
    const int pcol = pb * 8 + (lc & 7);
#pragma unroll
    for (int mt = 0; mt < 4; mt++) {
#pragma unroll
      for (int r = 0; r < 4; r++) {
        float v = acc[mt][nt][r] + bv;
        if (ACT == 1) {
          float y = 0.7978845608028654f * (v + 0.044715f * v * v * v);
          float t = 1.f - 2.f / (1.f + __expf(2.f * y));  // tanh(y)
          v = 0.5f * v * (1.f + t);
        }
        Cs[(lr0 + mt * 16 + r) * 128 + pcol] = f2b(v);
      }
    }
  }
  __syncthreads();
  const int cr = tid >> 4;        // row within 16-row pass
  const int lb = tid & 15;        // logical 16B block
#pragma unroll
  for (int ps = 0; ps < 8; ps++) {
    const int row_l = ps * 16 + cr;
    const int pb = (lb + (cr >> 2) * 2) & 15;
    uint4 val = *(const uint4*)&Cs[row_l * 128 + pb * 8];
    *(uint4*)&C[(size_t)(tm * 128 + row_l) * N + tn * 128 + lb * 8] = val;
  }
}

// ---------------- MFMA attention: one block per (b,h) ----------------
__global__ __launch_bounds__(256) void attn_kernel(
    const u16* __restrict__ qkv, const float* __restrict__ rel,
    u16* __restrict__ ctx) {
  __shared__ __align__(16) u16 qs[4096];
  __shared__ __align__(16) u16 ks[4096];
  __shared__ __align__(16) u16 vt[64 * 72];      // V^T [hd][key], pad 72
  __shared__ __align__(16) u16 ps[4 * 16 * 72];  // per-wave P [q][key], pad 72
  const int tid = threadIdx.x;
  const int lane = tid & 63;
  const int wave = tid >> 6;
  const int quad = lane >> 4;
  const int l15 = lane & 15;
  const int bh = blockIdx.x;
  const int b = bh >> 4, h = bh & 15;
  const size_t base = (size_t)b * 64 * 3072 + h * 64;

  {
    const int cA = tid, cB = tid + 256;
    const int rA = cA >> 3, sA = ((cA & 7) - rA) & 7;
    const int rB = cB >> 3, sB = ((cB & 7) - rB) & 7;
    const u16* gA = qkv + base + (size_t)rA * 3072 + sA * 8;
    const u16* gB = qkv + base + (size_t)rB * 3072 + sB * 8;
    gld16(gA, &qs[wave * 512]);
    gld16(gB, &qs[2048 + wave * 512]);
    gld16(gA + 1024, &ks[wave * 512]);
    gld16(gB + 1024, &ks[2048 + wave * 512]);
  }
  {
    const int hd = tid & 63;
    const int kg0 = tid >> 6;
#pragma unroll
    for (int half = 0; half < 2; half++) {
      const int kg = kg0 + half * 4;
      union { u16 s[8]; uint4 u; } o;
#pragma unroll
      for (int t = 0; t < 8; t++)
        o.s[t] = qkv[base + (size_t)(kg * 8 + t) * 3072 + 2048 + hd];
      *(uint4*)&vt[hd * 72 + kg * 8] = o.u;
    }
  }
  __syncthreads();

  const int qrow = wave * 16 + l15;
  bf16x8 aq[2];
#pragma unroll
  for (int kc = 0; kc < 2; kc++)
    aq[kc] = frag8(&qs[qrow * 64 + (((kc * 4 + quad) + qrow) & 7) * 8]);
  f32x4 accs[4] = {};
#pragma unroll
  for (int nt = 0; nt < 4; nt++) {
    const int krow = nt * 16 + l15;
#pragma unroll
    for (int kc = 0; kc < 2; kc++) {
      bf16x8 bk = frag8(&ks[krow * 64 + (((kc * 4 + quad) + krow) & 7) * 8]);
      accs[nt] =
          __builtin_amdgcn_mfma_f32_16x16x32_bf16(aq[kc], bk, accs[nt], 0, 0, 0);
    }
  }

  const int qg = wave * 16 + quad * 4;
  float pm[4][4], mx[4], sm[4];
#pragma unroll
  for (int r = 0; r < 4; r++) mx[r] = -1e30f;
#pragma unroll
  for (int nt = 0; nt < 4; nt++) {
    const float* rb = &rel[((size_t)h * 64 + qg) * 64 + nt * 16 + l15];
#pragma unroll
    for (int r = 0; r < 4; r++) {
      float v = accs[nt][r] * 0.125f + rb[r * 64];
      pm[nt][r] = v;
      mx[r] = fmaxf(mx[r], v);
    }
  }
#pragma unroll
  for (int r = 0; r < 4; r++) {
    mx[r] = fmaxf(mx[r], __shfl_xor(mx[r], 1));
    mx[r] = fmaxf(mx[r], __shfl_xor(mx[r], 2));
    mx[r] = fmaxf(mx[r], __shfl_xor(mx[r], 4));
    mx[r] = fmaxf(mx[r], __shfl_xor(mx[r], 8));
    sm[r] = 0.f;
  }
#pragma unroll
  for (int nt = 0; nt < 4; nt++)
#pragma unroll
    for (int r = 0; r < 4; r++) {
      float e = __expf(pm[nt][r] - mx[r]);
      pm[nt][r] = e;
      sm[r] += e;
    }
#pragma unroll
  for (int r = 0; r < 4; r++) {
    sm[r] += __shfl_xor(sm[r], 1);
    sm[r] += __shfl_xor(sm[r], 2);
    sm[r] += __shfl_xor(sm[r], 4);
    sm[r] += __shfl_xor(sm[r], 8);
    sm[r] = 1.f / sm[r];
  }
  u16* psw = &ps[wave * 1152];
#pragma unroll
  for (int nt = 0; nt < 4; nt++)
#pragma unroll
    for (int r = 0; r < 4; r++)
      psw[(quad * 4 + r) * 72 + nt * 16 + l15] = f2b(pm[nt][r] * sm[r]);
  __syncthreads();

  bf16x8 ap[2];
#pragma unroll
  for (int kc = 0; kc < 2; kc++)
    ap[kc] = frag8(&psw[l15 * 72 + kc * 32 + quad * 8]);
  f32x4 accc[4] = {};
#pragma unroll
  for (int nt = 0; nt < 4; nt++) {
    const int hdr = nt * 16 + l15;
#pragma unroll
    for (int kc = 0; kc < 2; kc++) {
      bf16x8 bv = frag8(&vt[hdr * 72 + kc * 32 + quad * 8]);
      accc[nt] =
          __builtin_amdgcn_mfma_f32_16x16x32_bf16(ap[kc], bv, accc[nt], 0, 0, 0);
    }
  }
#pragma unroll
  for (int nt = 0; nt < 4; nt++)
#pragma unroll
    for (int r = 0; r < 4; r++) {
      const int rowq = wave * 16 + quad * 4 + r;
      const int hd = nt * 16 + l15;
      qs[rowq * 64 + (((hd >> 3) + rowq) & 7) * 8 + (hd & 7)] = f2b(accc[nt][r]);
    }
  __syncthreads();
#pragma unroll
  for (int half = 0; half < 2; half++) {
    const int c = tid + half * 256;
    const int row = c >> 3, sub = c & 7;
    uint4 val = *(const uint4*)&qs[row * 64 + ((sub + row) & 7) * 8];
    *(uint4*)&ctx[(size_t)(b * 64 + row) * 1024 + h * 64 + sub * 8] = val;
  }
}

// ---------------- LN1: x1 = LN(x_bf16 + attn_bf16) -> bf16 ----------------
__global__ __launch_bounds__(256) void ln1_kernel(
    const u16* __restrict__ xres, const u16* __restrict__ add,
    const float* __restrict__ g, const float* __restrict__ be,
    u16* __restrict__ out) {
  const int row = blockIdx.x * 4 + (threadIdx.x >> 6);
  const int lane = threadIdx.x & 63;
  const u16* xr = xres + (size_t)row * 1024;
  const u16* ar = add + (size_t)row * 1024;
  float v[16];
  float sum = 0.f, sq = 0.f;
#pragma unroll
  for (int kk = 0; kk < 2; kk++) {
    const int cb = (lane + 64 * kk) * 8;
    uint4 xu = *(const uint4*)&xr[cb];
    uint4 au = *(const uint4*)&ar[cb];
    const u16* x8 = (const u16*)&xu;
    const u16* a8 = (const u16*)&au;
#pragma unroll
    for (int t = 0; t < 8; t++) {
      float f = b2f(x8[t]) + b2f(a8[t]);
      v[kk * 8 + t] = f;
      sum += f;
      sq += f * f;
    }
  }
#pragma unroll
  for (int o = 1; o < 64; o <<= 1) {
    sum += __shfl_xor(sum, o);
    sq += __shfl_xor(sq, o);
  }
  const float mean = sum * (1.f / 1024.f);
  const float var = sq * (1.f / 1024.f) - mean * mean;
  const float rstd = rsqrtf(var + 1e-5f);
#pragma unroll
  for (int kk = 0; kk < 2; kk++) {
    const int cb = (lane + 64 * kk) * 8;
    float4 ga = *(const float4*)&g[cb];
    float4 gb = *(const float4*)&g[cb + 4];
    float4 ba = *(const float4*)&be[cb];
    float4 bb = *(const float4*)&be[cb + 4];
    const float* vv = &v[kk * 8];
    union { u16 s[8]; uint4 u; } o8;
    o8.s[0] = f2b((vv[0] - mean) * rstd * ga.x + ba.x);
    o8.s[1] = f2b((vv[1] - mean) * rstd * ga.y + ba.y);
    o8.s[2] = f2b((vv[2] - mean) * rstd * ga.z + ba.z);
    o8.s[3] = f2b((vv[3] - mean) * rstd * ga.w + ba.w);
    o8.s[4] = f2b((vv[4] - mean) * rstd * gb.x + bb.x);
    o8.s[5] = f2b((vv[5] - mean) * rstd * gb.y + bb.y);
    o8.s[6] = f2b((vv[6] - mean) * rstd * gb.z + bb.z);
    o8.s[7] = f2b((vv[7] - mean) * rstd * gb.w + bb.w);
    *(uint4*)&out[(size_t)row * 1024 + cb] = o8.u;
  }
}

// ---------------- LN2: out = LN(x1_bf16 + ffn_bf16) -> fp32 (d_out) --------
__global__ __launch_bounds__(256) void ln2_kernel(
    const u16* __restrict__ xres, const u16* __restrict__ add,
    const float* __restrict__ g, const float* __restrict__ be,
    float* __restrict__ out) {
  const int row = blockIdx.x * 4 + (threadIdx.x >> 6);
  const int lane = threadIdx.x & 63;
  const u16* xr = xres + (size_t)row * 1024;
  const u16* ar = add + (size_t)row * 1024;
  float v[16];
  float sum = 0.f, sq = 0.f;
#pragma unroll
  for (int kk = 0; kk < 2; kk++) {
    const int cb = (lane + 64 * kk) * 8;
    uint4 xu = *(const uint4*)&xr[cb];
    uint4 au = *(const uint4*)&ar[cb];
    const u16* x8 = (const u16*)&xu;
    const u16* a8 = (const u16*)&au;
#pragma unroll
    for (int t = 0; t < 8; t++) {
      float f = b2f(x8[t]) + b2f(a8[t]);
      v[kk * 8 + t] = f;
      sum += f;
      sq += f * f;
    }
  }
#pragma unroll
  for (int o = 1; o < 64; o <<= 1) {
    sum += __shfl_xor(sum, o);
    sq += __shfl_xor(sq, o);
  }
  const float mean = sum * (1.f / 1024.f);
  const float var = sq * (1.f / 1024.f) - mean * mean;
  const float rstd = rsqrtf(var + 1e-5f);
#pragma unroll
  for (int kk = 0; kk < 2; kk++) {
    const int cb = (lane + 64 * kk) * 8;
    float4 ga = *(const float4*)&g[cb];
    float4 gb = *(const float4*)&g[cb + 4];
    float4 ba = *(const float4*)&be[cb];
    float4 bb = *(const float4*)&be[cb + 4];
    float4 o0, o1;
    o0.x = (v[kk * 8 + 0] - mean) * rstd * ga.x + ba.x;
    o0.y = (v[kk * 8 + 1] - mean) * rstd * ga.y + ba.y;
    o0.z = (v[kk * 8 + 2] - mean) * rstd * ga.z + ba.z;
    o0.w = (v[kk * 8 + 3] - mean) * rstd * ga.w + ba.w;
    o1.x = (v[kk * 8 + 4] - mean) * rstd * gb.x + bb.x;
    o1.y = (v[kk * 8 + 5] - mean) * rstd * gb.y + bb.y;
    o1.z = (v[kk * 8 + 6] - mean) * rstd * gb.z + bb.z;
    o1.w = (v[kk * 8 + 7] - mean) * rstd * gb.w + bb.w;
    *(float4*)&out[(size_t)row * 1024 + cb] = o0;
    *(float4*)&out[(size_t)row * 1024 + cb + 4] = o1;
  }
}

extern "C" void kernel_launch(void* const* d_in, const int* in_sizes, int n_in,
                              void* d_out, int out_size, void* d_ws,
                              size_t ws_size, hipStream_t stream) {
  const float* x = (const float*)d_in[0];
  const float* w_in = (const float*)d_in[1];
  const float* b_in = (const float*)d_in[2];
  const float* w_out = (const float*)d_in[3];
  const float* b_out = (const float*)d_in[4];
  const float* rel = (const float*)d_in[5];
  const float* g1 = (const float*)d_in[6];
  const float* be1 = (const float*)d_in[7];
  const float* w1 = (const float*)d_in[8];
  const float* b1 = (const float*)d_in[9];
  const float* w2 = (const float*)d_in[10];
  const float* b2 = (const float*)d_in[11];
  const float* g2 = (const float*)d_in[12];
  const float* be2 = (const float*)d_in[13];
  float* out = (float*)d_out;

  u16* ws = (u16*)d_ws;
  u16* xb = ws + 0;            // 8,388,608
  u16* winb = ws + 8388608;    // 3,145,728
  u16* woutb = ws + 11534336;  // 1,048,576
  u16* w1b = ws + 12582912;    // 4,194,304
  u16* w2b = ws + 16777216;    // 4,194,304
  u16* qkvb = ws + 20971520;   // 25,165,824  (h aliases qkv+ctx)
  u16* ctxb = ws + 46137344;   // 8,388,608
  u16* attnb = ws + 54525952;  // 8,388,608   (ffn aliases)
  u16* x1b = ws + 62914560;    // 8,388,608
  u16* hb = qkvb;
  u16* ffnb = attnb;

  Cvt5 ca;
  ca.s0 = x; ca.s1 = w_in; ca.s2 = w_out; ca.s3 = w1; ca.s4 = w2;
  ca.d0 = xb; ca.d1 = winb; ca.d2 = woutb; ca.d3 = w1b; ca.d4 = w2b;
  cvt5_kernel<<<10240, 256, 0, stream>>>(ca);

  gemm_bt<0><<<64 * 24, 256, 0, stream>>>(xb, winb, b_in, qkvb, 3072, 1024);

  attn_kernel<<<2048, 256, 0, stream>>>(qkvb, rel, ctxb);

  gemm_bt<0><<<64 * 8, 256, 0, stream>>>(ctxb, woutb, b_out, attnb, 1024, 1024);

  ln1_kernel<<<2048, 256, 0, stream>>>(xb, attnb, g1, be1, x1b);

  gemm_bt<1><<<64 * 32, 256, 0, stream>>>(x1b, w1b, b1, hb, 4096, 1024);

  gemm_bt<0><<<64 * 8, 256, 0, stream>>>(hb, w2b, b2, ffnb, 1024, 4096);

  ln2_kernel<<<2048, 256, 0, stream>>>(x1b, ffnb, g2, be2, out);
}